// Round 11
// baseline (912.775 us; speedup 1.0000x reference)
//
#include <hip/hip_runtime.h>

// GraphSAGE 3-layer forward on MI355X.
// CSR build (dst-grouped) once per call, then per layer:
//   aggregate: h_neigh[v] = mean_{u in N_in(v)} h[u]  (f32 gather; writes bf16 hi/lo split)
//   gemm:      out = [h | h_neigh](N x 256) @ [Ws; Wn](256 x Fo) + b (+ReLU)
//              via split-bf16 MFMA: C = Ahi*Whi + Alo*Whi + Ahi*Wlo
//
// R2:  single-block scan was top dispatch (191us, 0.17% occ) -> parallel scan (R5: 1102->923).
// R5:  gemm top (140us/layer, VALUBusy 64%, MfmaUtil 0) -> MFMA split-bf16 (R10).
// R10: gemm STILL 143us but VALUBusy 6.6%, MfmaUtil 5.3%, HBM 9% -> latency-bound:
//      128 W-fragment reloads/wave + VGPR=56 (no ILP) + 2.4 waves/SIMD.
// R11: persistent-W gemm: W frags pinned in regs (16 loads/wave total), grid-stride
//      over row-tiles, 2 interleaved row-tiles/wave for ILP. Activations PRE-SPLIT
//      to bf16 hi/lo by producers (asplit for inputs; aggregate + gemm epilogues),
//      so the gemm inner loop is pure {2 loads + 3 MFMAs} per kstep per tile.

#define F_IN 128
#define SCAN_CHUNK 1024

typedef __attribute__((ext_vector_type(8))) short bf16x8;
typedef __attribute__((ext_vector_type(4))) float f32x4;

__device__ __forceinline__ unsigned short f32_to_bf16_rne(float x) {
    unsigned int u = __float_as_uint(x);
    unsigned int r = u + 0x7FFFu + ((u >> 16) & 1u);   // round-to-nearest-even
    return (unsigned short)(r >> 16);
}
__device__ __forceinline__ float bf16_bits_to_f32(unsigned short h) {
    return __uint_as_float(((unsigned int)h) << 16);
}

// ---------------- CSR build ----------------

__global__ __launch_bounds__(256) void count_deg_kernel(
    const int* __restrict__ dst, int* __restrict__ cnt, int E) {
    int i = blockIdx.x * 256 + threadIdx.x;
    if (i < E) atomicAdd(&cnt[dst[i]], 1);
}

__global__ __launch_bounds__(256) void scan_part1(
    const int* __restrict__ cnt, int* __restrict__ bsum, int n) {
    __shared__ int red[4];
    int base = blockIdx.x * SCAN_CHUNK + threadIdx.x * 4;
    int s = 0;
    if (base + 4 <= n) {
        int4 v = *(const int4*)&cnt[base];
        s = v.x + v.y + v.z + v.w;
    } else {
        for (int j = 0; j < 4; ++j) if (base + j < n) s += cnt[base + j];
    }
    for (int off = 32; off > 0; off >>= 1) s += __shfl_down(s, off, 64);
    if ((threadIdx.x & 63) == 0) red[threadIdx.x >> 6] = s;
    __syncthreads();
    if (threadIdx.x == 0)
        bsum[blockIdx.x] = red[0] + red[1] + red[2] + red[3];
}

__global__ __launch_bounds__(256) void scan_part2(int* __restrict__ bsum, int nb) {
    __shared__ int tmp[256];
    int t = threadIdx.x;
    tmp[t] = (t < nb) ? bsum[t] : 0;
    __syncthreads();
    for (int off = 1; off < 256; off <<= 1) {
        int x = tmp[t];
        int add = (t >= off) ? tmp[t - off] : 0;
        __syncthreads();
        tmp[t] = x + add;
        __syncthreads();
    }
    if (t < nb) bsum[t] = (t == 0) ? 0 : tmp[t - 1];
}

__global__ __launch_bounds__(256) void scan_part3(
    const int* __restrict__ cnt, const int* __restrict__ bsum,
    int* __restrict__ row_ptr, int n, int E) {
    __shared__ int tsum[256];
    int t = threadIdx.x;
    int base = blockIdx.x * SCAN_CHUNK + t * 4;
    int c[4];
    int s = 0;
    #pragma unroll
    for (int j = 0; j < 4; ++j) {
        int idx = base + j;
        c[j] = (idx < n) ? cnt[idx] : 0;
        s += c[j];
    }
    tsum[t] = s;
    __syncthreads();
    for (int off = 1; off < 256; off <<= 1) {
        int x = tsum[t];
        int add = (t >= off) ? tsum[t - off] : 0;
        __syncthreads();
        tsum[t] = x + add;
        __syncthreads();
    }
    int p = bsum[blockIdx.x] + ((t == 0) ? 0 : tsum[t - 1]);
    #pragma unroll
    for (int j = 0; j < 4; ++j) {
        int idx = base + j;
        if (idx < n) { row_ptr[idx] = p; p += c[j]; }
    }
    if (blockIdx.x == 0 && t == 0) row_ptr[n] = E;
}

__global__ __launch_bounds__(256) void fill_kernel(
    const int* __restrict__ src, const int* __restrict__ dst,
    const int* __restrict__ row_ptr, int* __restrict__ cursor,
    int* __restrict__ col, int E) {
    int i = blockIdx.x * 256 + threadIdx.x;
    if (i < E) {
        int d = dst[i];
        int pos = atomicAdd(&cursor[d], 1);
        col[row_ptr[d] + pos] = src[i];
    }
}

// ---------------- activation split (f32 -> bf16 hi/lo) ----------------
// thread i handles 8 consecutive values; vectorized 16B loads/stores.
__global__ __launch_bounds__(256) void asplit_kernel(
    const float* __restrict__ in, unsigned short* __restrict__ hi,
    unsigned short* __restrict__ lo, int total8) {
    int i = blockIdx.x * 256 + threadIdx.x;
    if (i >= total8) return;
    const float4* p = (const float4*)in;
    float4 a = p[2 * i], b = p[2 * i + 1];
    float v[8] = {a.x, a.y, a.z, a.w, b.x, b.y, b.z, b.w};
    unsigned int h[8], l[8];
    #pragma unroll
    for (int j = 0; j < 8; ++j) {
        h[j] = f32_to_bf16_rne(v[j]);
        l[j] = f32_to_bf16_rne(v[j] - bf16_bits_to_f32((unsigned short)h[j]));
    }
    uint4 H, L;
    H.x = h[0] | (h[1] << 16); H.y = h[2] | (h[3] << 16);
    H.z = h[4] | (h[5] << 16); H.w = h[6] | (h[7] << 16);
    L.x = l[0] | (l[1] << 16); L.y = l[2] | (l[3] << 16);
    L.z = l[4] | (l[5] << 16); L.w = l[6] | (l[7] << 16);
    ((uint4*)hi)[i] = H;
    ((uint4*)lo)[i] = L;
}

// ---------------- aggregation ----------------
// One 32-lane group per node; f32 gather (4-way unrolled); epilogue writes
// the mean pre-split as bf16 hi/lo (feeds the gemm's An operand directly).
__global__ __launch_bounds__(256) void aggregate_kernel(
    const float* __restrict__ h, const int* __restrict__ row_ptr,
    const int* __restrict__ col, unsigned short* __restrict__ hn_hi,
    unsigned short* __restrict__ hn_lo, int n) {
    int g = (blockIdx.x * 256 + threadIdx.x) >> 5;
    int lane = threadIdx.x & 31;
    if (g >= n) return;
    int s = row_ptr[g], e = row_ptr[g + 1];
    const float4* h4 = (const float4*)h;
    float4 acc = make_float4(0.f, 0.f, 0.f, 0.f);
    int i = s;
    for (; i + 3 < e; i += 4) {
        int u0 = col[i], u1 = col[i + 1], u2 = col[i + 2], u3 = col[i + 3];
        float4 x0 = h4[(size_t)u0 * 32 + lane];
        float4 x1 = h4[(size_t)u1 * 32 + lane];
        float4 x2 = h4[(size_t)u2 * 32 + lane];
        float4 x3 = h4[(size_t)u3 * 32 + lane];
        acc.x += (x0.x + x1.x) + (x2.x + x3.x);
        acc.y += (x0.y + x1.y) + (x2.y + x3.y);
        acc.z += (x0.z + x1.z) + (x2.z + x3.z);
        acc.w += (x0.w + x1.w) + (x2.w + x3.w);
    }
    for (; i < e; ++i) {
        int u = col[i];
        float4 x = h4[(size_t)u * 32 + lane];
        acc.x += x.x; acc.y += x.y; acc.z += x.z; acc.w += x.w;
    }
    float inv = 1.f / fmaxf((float)(e - s), 1.f);
    float r[4] = {acc.x * inv, acc.y * inv, acc.z * inv, acc.w * inv};
    unsigned int hh[4], ll[4];
    #pragma unroll
    for (int j = 0; j < 4; ++j) {
        hh[j] = f32_to_bf16_rne(r[j]);
        ll[j] = f32_to_bf16_rne(r[j] - bf16_bits_to_f32((unsigned short)hh[j]));
    }
    uint2 H, L;
    H.x = hh[0] | (hh[1] << 16); H.y = hh[2] | (hh[3] << 16);
    L.x = ll[0] | (ll[1] << 16); L.y = ll[2] | (ll[3] << 16);
    *(uint2*)(hn_hi + (size_t)g * 128 + lane * 4) = H;
    *(uint2*)(hn_lo + (size_t)g * 128 + lane * 4) = L;
}

// ---------------- W split/transpose ----------------
// Wt_hi/Wt_lo [fopad][256] bf16; Wt[c][k] = (k<128 ? Ws[k][c] : Wn[k-128][c]).
__global__ __launch_bounds__(256) void wsplit_kernel(
    const float* __restrict__ Ws, const float* __restrict__ Wn,
    unsigned short* __restrict__ hi, unsigned short* __restrict__ lo,
    int fo, int fopad) {
    int i = blockIdx.x * 256 + threadIdx.x;
    if (i >= fopad * 256) return;
    int c = i >> 8, k = i & 255;
    float v = 0.f;
    if (c < fo) v = (k < 128) ? Ws[(size_t)k * fo + c] : Wn[(size_t)(k - 128) * fo + c];
    unsigned short h = f32_to_bf16_rne(v);
    unsigned short l = f32_to_bf16_rne(v - bf16_bits_to_f32(h));
    hi[i] = h; lo[i] = l;
}

// ---------------- persistent-W split-bf16 MFMA GEMM ----------------
// 512 threads = 8 waves. Wave -> col-tile ct = wid & (NCT-1), row-group
// rg = wid / NCT. Wave pins its 16 W fragments (8 kstep x hi/lo = 64 VGPR)
// in registers ONCE, then grid-strides over row-tiles, 2 interleaved 16-row
// tiles per step (independent MFMA chains for ILP). Inner loop per kstep:
// 4 x 16B loads + 6 MFMA, zero VALU (activations pre-split).
// Frag layouts (R10-validated on HW): A row=l&15,k=(l>>4)*8+j; B col=l&15,
// same k; C/D col=l&15,row=(l>>4)*4+reg.
template <int NCT, bool RELU, bool WSPLIT>
__global__ __launch_bounds__(512) void gemm_pw_kernel(
    const unsigned short* __restrict__ Shi, const unsigned short* __restrict__ Slo,
    const unsigned short* __restrict__ Nhi, const unsigned short* __restrict__ Nlo,
    const unsigned short* __restrict__ Whi, const unsigned short* __restrict__ Wlo,
    const float* __restrict__ bias, float* __restrict__ out,
    unsigned short* __restrict__ Ohi, unsigned short* __restrict__ Olo,
    int n, int fo) {
    constexpr int RG = 8 / NCT;      // row-groups per block
    constexpr int BR = 32 * RG;      // rows per block-step (2 tiles/wave)
    int wid = threadIdx.x >> 6, lane = threadIdx.x & 63;
    int r16 = lane & 15, kg = lane >> 4;
    int ct = wid & (NCT - 1), rg = wid / NCT;
    int c = ct * 16 + r16;
    float bv = (c < fo) ? bias[c] : 0.f;

    bf16x8 wh[8], wl[8];
    #pragma unroll
    for (int ks = 0; ks < 8; ++ks) {
        wh[ks] = *(const bf16x8*)(Whi + (size_t)c * 256 + ks * 32 + kg * 8);
        wl[ks] = *(const bf16x8*)(Wlo + (size_t)c * 256 + ks * 32 + kg * 8);
    }

    int ntiles = (n + BR - 1) / BR;
    for (int tt = blockIdx.x; tt < ntiles; tt += gridDim.x) {
        int rowbase = tt * BR + rg * 32;
        int ar0 = rowbase + r16;      if (ar0 > n - 1) ar0 = n - 1;
        int ar1 = rowbase + 16 + r16; if (ar1 > n - 1) ar1 = n - 1;
        f32x4 acc0 = (f32x4){0.f, 0.f, 0.f, 0.f};
        f32x4 acc1 = (f32x4){0.f, 0.f, 0.f, 0.f};
        #pragma unroll
        for (int ks = 0; ks < 8; ++ks) {
            const unsigned short* hs = (ks < 4) ? Shi : Nhi;
            const unsigned short* ls = (ks < 4) ? Slo : Nlo;
            size_t o0 = (size_t)ar0 * 128 + (ks & 3) * 32 + kg * 8;
            size_t o1 = (size_t)ar1 * 128 + (ks & 3) * 32 + kg * 8;
            bf16x8 ah0 = *(const bf16x8*)(hs + o0);
            bf16x8 al0 = *(const bf16x8*)(ls + o0);
            bf16x8 ah1 = *(const bf16x8*)(hs + o1);
            bf16x8 al1 = *(const bf16x8*)(ls + o1);
            acc0 = __builtin_amdgcn_mfma_f32_16x16x32_bf16(ah0, wh[ks], acc0, 0, 0, 0);
            acc1 = __builtin_amdgcn_mfma_f32_16x16x32_bf16(ah1, wh[ks], acc1, 0, 0, 0);
            acc0 = __builtin_amdgcn_mfma_f32_16x16x32_bf16(al0, wh[ks], acc0, 0, 0, 0);
            acc1 = __builtin_amdgcn_mfma_f32_16x16x32_bf16(al1, wh[ks], acc1, 0, 0, 0);
            acc0 = __builtin_amdgcn_mfma_f32_16x16x32_bf16(ah0, wl[ks], acc0, 0, 0, 0);
            acc1 = __builtin_amdgcn_mfma_f32_16x16x32_bf16(ah1, wl[ks], acc1, 0, 0, 0);
        }
        #pragma unroll
        for (int m = 0; m < 2; ++m) {
            f32x4 acc = m ? acc1 : acc0;   // m is compile-time after unroll
            #pragma unroll
            for (int i = 0; i < 4; ++i) {
                int node = rowbase + m * 16 + kg * 4 + i;
                if (node < n && c < fo) {
                    float v = acc[i] + bv;
                    if (RELU) v = fmaxf(v, 0.f);
                    out[(size_t)node * fo + c] = v;
                    if (WSPLIT) {
                        unsigned short hh = f32_to_bf16_rne(v);
                        Ohi[(size_t)node * 128 + c] = hh;
                        Olo[(size_t)node * 128 + c] =
                            f32_to_bf16_rne(v - bf16_bits_to_f32(hh));
                    }
                }
            }
        }
    }
}

static inline size_t align256(size_t x) { return (x + 255) & ~(size_t)255; }
static inline int imin(int a, int b) { return a < b ? a : b; }

extern "C" void kernel_launch(void* const* d_in, const int* in_sizes, int n_in,
                              void* d_out, int out_size, void* d_ws, size_t ws_size,
                              hipStream_t stream) {
    const float* inputs = (const float*)d_in[0];
    const int* src = (const int*)d_in[1];
    const int* dst = (const int*)d_in[2];
    const float* Ws0 = (const float*)d_in[3];
    const float* Wn0 = (const float*)d_in[4];
    const float* b0  = (const float*)d_in[5];
    const float* Ws1 = (const float*)d_in[6];
    const float* Wn1 = (const float*)d_in[7];
    const float* b1  = (const float*)d_in[8];
    const float* Ws2 = (const float*)d_in[9];
    const float* Wn2 = (const float*)d_in[10];
    const float* b2  = (const float*)d_in[11];

    const int N = in_sizes[0] / F_IN;   // 100000
    const int E = in_sizes[1];          // 1600000

    // Workspace layout (256B-aligned). split0 is shared: asplit(inputs) writes it,
    // gemm0 reads it; gemm1 overwrites it with bufB's split (inputs-split dead by then),
    // gemm2 reads it.
    char* ws = (char*)d_ws;
    size_t off = 0;
    size_t off_cnt    = off; off += align256((size_t)N * 4);
    size_t off_cursor = off; off += align256((size_t)N * 4);
    size_t zero_bytes = off;                       // cnt + cursor get memset(0)
    size_t off_rowptr = off; off += align256(((size_t)N + 1) * 4);
    size_t off_bsum   = off; off += align256(1024 * 4);
    size_t off_col    = off; off += align256((size_t)E * 4);
    size_t off_bufA   = off; off += align256((size_t)N * F_IN * 4);  // f32 (gather src)
    size_t off_bufB   = off; off += align256((size_t)N * F_IN * 4);  // f32 (gather src)
    size_t off_s0h    = off; off += align256((size_t)N * F_IN * 2);  // inputs/bufB hi
    size_t off_s0l    = off; off += align256((size_t)N * F_IN * 2);  // inputs/bufB lo
    size_t off_s1h    = off; off += align256((size_t)N * F_IN * 2);  // bufA hi
    size_t off_s1l    = off; off += align256((size_t)N * F_IN * 2);  // bufA lo
    size_t off_hnh    = off; off += align256((size_t)N * F_IN * 2);  // hneigh hi
    size_t off_hnl    = off; off += align256((size_t)N * F_IN * 2);  // hneigh lo
    size_t off_wt0h   = off; off += align256(128 * 256 * 2);
    size_t off_wt0l   = off; off += align256(128 * 256 * 2);
    size_t off_wt1h   = off; off += align256(128 * 256 * 2);
    size_t off_wt1l   = off; off += align256(128 * 256 * 2);
    size_t off_wt2h   = off; off += align256(64 * 256 * 2);
    size_t off_wt2l   = off; off += align256(64 * 256 * 2);
    (void)ws_size;

    int*   cnt    = (int*)(ws + off_cnt);
    int*   cursor = (int*)(ws + off_cursor);
    int*   rowptr = (int*)(ws + off_rowptr);
    int*   bsum   = (int*)(ws + off_bsum);
    int*   col    = (int*)(ws + off_col);
    float* bufA   = (float*)(ws + off_bufA);
    float* bufB   = (float*)(ws + off_bufB);
    unsigned short* s0h = (unsigned short*)(ws + off_s0h);
    unsigned short* s0l = (unsigned short*)(ws + off_s0l);
    unsigned short* s1h = (unsigned short*)(ws + off_s1h);
    unsigned short* s1l = (unsigned short*)(ws + off_s1l);
    unsigned short* hnh = (unsigned short*)(ws + off_hnh);
    unsigned short* hnl = (unsigned short*)(ws + off_hnl);
    unsigned short* wt0h = (unsigned short*)(ws + off_wt0h);
    unsigned short* wt0l = (unsigned short*)(ws + off_wt0l);
    unsigned short* wt1h = (unsigned short*)(ws + off_wt1h);
    unsigned short* wt1l = (unsigned short*)(ws + off_wt1l);
    unsigned short* wt2h = (unsigned short*)(ws + off_wt2h);
    unsigned short* wt2l = (unsigned short*)(ws + off_wt2l);
    float* out    = (float*)d_out;

    hipMemsetAsync(ws, 0, zero_bytes, stream);

    int eb = (E + 255) / 256;
    int nb = (N + SCAN_CHUNK - 1) / SCAN_CHUNK;

    count_deg_kernel<<<eb, 256, 0, stream>>>(dst, cnt, E);
    scan_part1<<<nb, 256, 0, stream>>>(cnt, bsum, N);
    scan_part2<<<1, 256, 0, stream>>>(bsum, nb);
    scan_part3<<<nb, 256, 0, stream>>>(cnt, bsum, rowptr, N, E);
    fill_kernel<<<eb, 256, 0, stream>>>(src, dst, rowptr, cursor, col, E);

    // inputs -> bf16 hi/lo (once); W split/transpose (tiny)
    int total8 = N * (F_IN / 8);
    asplit_kernel<<<(total8 + 255) / 256, 256, 0, stream>>>(inputs, s0h, s0l, total8);
    wsplit_kernel<<<(128 * 256) / 256, 256, 0, stream>>>(Ws0, Wn0, wt0h, wt0l, 128, 128);
    wsplit_kernel<<<(128 * 256) / 256, 256, 0, stream>>>(Ws1, Wn1, wt1h, wt1l, 128, 128);
    wsplit_kernel<<<(64 * 256) / 256, 256, 0, stream>>>(Ws2, Wn2, wt2h, wt2l, 40, 64);

    int ab = (N * 32 + 255) / 256;              // aggregate: 32 lanes per node
    int g01 = imin((N + 31) / 32, 1024);        // gemm layers 0/1: 32 rows/block-step
    int g2  = imin((N + 63) / 64, 1024);        // gemm layer 2:  64 rows/block-step

    // Layer 0
    aggregate_kernel<<<ab, 256, 0, stream>>>(inputs, rowptr, col, hnh, hnl, N);
    gemm_pw_kernel<8, true, true><<<g01, 512, 0, stream>>>(
        s0h, s0l, hnh, hnl, wt0h, wt0l, b0, bufA, s1h, s1l, N, 128);

    // Layer 1 (writes bufB f32 + its split into s0 — inputs-split dead now)
    aggregate_kernel<<<ab, 256, 0, stream>>>(bufA, rowptr, col, hnh, hnl, N);
    gemm_pw_kernel<8, true, true><<<g01, 512, 0, stream>>>(
        s1h, s1l, hnh, hnl, wt1h, wt1l, b1, bufB, s0h, s0l, N, 128);

    // Layer 2 (40 classes padded to 64; NCT=4, 2 row-groups)
    aggregate_kernel<<<ab, 256, 0, stream>>>(bufB, rowptr, col, hnh, hnl, N);
    gemm_pw_kernel<4, false, false><<<g2, 512, 0, stream>>>(
        s0h, s0l, hnh, hnl, wt2h, wt2l, b2, out, (unsigned short*)nullptr,
        (unsigned short*)nullptr, N, 40);
}